// Round 1
// 80.593 us; speedup vs baseline: 1.0271x; 1.0271x over previous
//
#include <hip/hip_runtime.h>

#define EPSF 1e-7f
#define TS2 72   // bf16 row stride: 64 + 8 pad (16B-aligned rows, bank-rotating)

typedef __bf16 bf16;
typedef __attribute__((ext_vector_type(8))) __bf16 bf16x8;
typedef __attribute__((ext_vector_type(4))) __bf16 bf16x4;
typedef __attribute__((ext_vector_type(4))) float f32x4;

// Sum over each 16-lane group via DPP involutions. Zero LDS traffic.
__device__ __forceinline__ float dpp_sum16(float v) {
  int x;
  x = __builtin_amdgcn_update_dpp(0, __builtin_bit_cast(int, v), 0xB1, 0xf, 0xf, true);
  v += __builtin_bit_cast(float, x);                     // + lane^1
  x = __builtin_amdgcn_update_dpp(0, __builtin_bit_cast(int, v), 0x4E, 0xf, 0xf, true);
  v += __builtin_bit_cast(float, x);                     // + lane^2
  x = __builtin_amdgcn_update_dpp(0, __builtin_bit_cast(int, v), 0x141, 0xf, 0xf, true);
  v += __builtin_bit_cast(float, x);                     // + lane^7 (half mirror)
  x = __builtin_amdgcn_update_dpp(0, __builtin_bit_cast(int, v), 0x140, 0xf, 0xf, true);
  v += __builtin_bit_cast(float, x);                     // + lane^15 (mirror)
  return v;
}

// factor(dot) = acos(dot)/sqrt(1-dot^2) = theta/sin(theta), fused via
// A&S 4.4.45: acos(x)=sqrt(1-x)*P(x) for x>=0. Then
//   dot>=0: P(dot)*rsqrt(1+dot)
//   dot< 0: (pi*rsqrt(1-|dot|) - P(|dot|)) * rsqrt(1+|dot|)
// 2 v_rsq + ~7 VALU.
__device__ __forceinline__ float fused_factor(float dot) {
  float ax = fabsf(dot);
  float q2 = __builtin_amdgcn_rsqf(1.0f + ax);
  float r2 = __builtin_amdgcn_rsqf(1.0f - ax);   // dot clamped -> 1-ax >= EPSF
  float pa = fmaf(fmaf(fmaf(-0.0187292994f, ax, 0.0742610070f), ax,
                       -0.2121144013f), ax, 1.5707288f);
  float sel = (dot < 0.0f) ? fmaf(3.14159265358979f, r2, -pa) : pa;
  return sel * q2;
}

// One block = one sample n; 4 waves; wave wv owns o-rows [16wv,16wv+16).
// it0 SPECIALIZED: a0 == x0 for every o, so dot[o][i] = <x0,x_i> is rank-1.
//   GEMM1-it0 + 16 factor evals collapse to a VALU dot (same bf16 operands
//   the MFMA would have consumed) + shfl butterfly + 4 factor evals.
// it1/it2 (MFMA path):
//   GEMM1: dotT[o][i] = sum_dd a[o][dd]*x[i][dd]  (A=AC(Arow), B=xrf regs)
//   GEMM2: G[o][dd]   = sum_i  c[i][o]*x[i][dd]   (A=AC(Ct),   B=Xt)
// Barrier schedule: [stage Xrow] sync [xrf/x0 hoist + Xt build + it0 front]
// sync-once [GEMM2 it0; iters 1,2 barrier-free] [direct-store epilogue, no sync].
__global__ __launch_bounds__(256, 4) void mfd_fc_mfma(
    const float* __restrict__ x, const float* __restrict__ wraw,
    float* __restrict__ out) {
  __shared__ __align__(16) char smem[3 * 64 * TS2 * sizeof(bf16)];  // 27648 B
  bf16* Xrow = (bf16*)smem;            // [i][dd]
  bf16* Xt   = Xrow + 64 * TS2;        // [dd][i]
  bf16* AC   = Xt + 64 * TS2;          // [o][dd] as Arow / [o][i] as Ct

  const int n = blockIdx.x;
  const int tid = threadIdx.x;
  const int wv = tid >> 6;
  const int lane = tid & 63;
  const int ln15 = lane & 15;
  const int quad = lane >> 4;
  const int obase = 16 * wv + 4 * quad;
  const float* xn = x + (size_t)n * 4096;

  // ---- stage X -> Xrow (bf16), coalesced float4 loads ----
#pragma unroll
  for (int t = 0; t < 4; ++t) {
    int idx = tid + t * 256;  // float4 index
    int i = idx >> 4;
    int c4 = (idx & 15) << 2;
    float4 v = reinterpret_cast<const float4*>(xn)[idx];
    bf16x4 b;
    b[0] = (bf16)v.x; b[1] = (bf16)v.y; b[2] = (bf16)v.z; b[3] = (bf16)v.w;
    *reinterpret_cast<bf16x4*>(&Xrow[i * TS2 + c4]) = b;
  }

  // ---- per-wave softmax of wraw columns [obase..obase+3] ----
  float wf[4][4];
  {
    float cs[4] = {0.f, 0.f, 0.f, 0.f};
#pragma unroll
    for (int t = 0; t < 4; ++t) {
      float4 wr = *reinterpret_cast<const float4*>(&wraw[(16 * t + ln15) * 64 + obase]);
      wf[t][0] = __expf(wr.x); wf[t][1] = __expf(wr.y);
      wf[t][2] = __expf(wr.z); wf[t][3] = __expf(wr.w);
#pragma unroll
      for (int r = 0; r < 4; ++r) cs[r] += wf[t][r];
    }
#pragma unroll
    for (int r = 0; r < 4; ++r) {
      float inv = __builtin_amdgcn_rcpf(dpp_sum16(cs[r]));
#pragma unroll
      for (int t = 0; t < 4; ++t) wf[t][r] *= inv;
    }
  }

  // ---- a := x0 (fp32 registers only; no AC init — it0 GEMM1 specialized away)
  float a_reg[4][4];
#pragma unroll
  for (int t = 0; t < 4; ++t) {
    float v = xn[16 * t + ln15];
#pragma unroll
    for (int r = 0; r < 4; ++r) a_reg[t][r] = v;
  }

  __syncthreads();  // Xrow complete

  // ---- hoist GEMM1 B-fragments (Xrow is loop-invariant): 8 x bf16x8 ----
  bf16x8 xrf[4][2];
#pragma unroll
  for (int t = 0; t < 4; ++t)
#pragma unroll
    for (int ks = 0; ks < 2; ++ks)
      xrf[t][ks] = *reinterpret_cast<const bf16x8*>(
          &Xrow[(16 * t + ln15) * TS2 + ks * 32 + quad * 8]);

  // ---- x0 fragment (row 0; per-quad broadcast read) for the it0 rank-1 dot
  bf16x8 x0f[2];
#pragma unroll
  for (int ks = 0; ks < 2; ++ks)
    x0f[ks] = *reinterpret_cast<const bf16x8*>(&Xrow[ks * 32 + quad * 8]);

  // ---- build Xt from Xrow (u16 column reads = pair-broadcast) ----
  {
    int dd = tid & 63, ih = tid >> 6;  // i-range [16*ih, 16*ih+16)
    bf16 tmp[16];
#pragma unroll
    for (int j = 0; j < 16; ++j) tmp[j] = Xrow[(16 * ih + j) * TS2 + dd];
    *reinterpret_cast<bf16x8*>(&Xt[dd * TS2 + 16 * ih]) =
        *reinterpret_cast<bf16x8*>(&tmp[0]);
    *reinterpret_cast<bf16x8*>(&Xt[dd * TS2 + 16 * ih + 8]) =
        *reinterpret_cast<bf16x8*>(&tmp[8]);
  }
  // NOTE: no barrier yet — it0 front only touches Xrow-derived regs + AC.

  const bf16* acbase = &AC[(16 * wv + ln15) * TS2];

  for (int it = 0; it < 3; ++it) {
    float sd[4] = {0.f, 0.f, 0.f, 0.f};
    if (it == 0) {
      // ---- rank-1 it0: dot[o][i] = <x0, x_i>, independent of o ----
#pragma unroll
      for (int t = 0; t < 4; ++t) {
        float p = 0.f;
#pragma unroll
        for (int ks = 0; ks < 2; ++ks)
#pragma unroll
          for (int j = 0; j < 8; ++j)
            p = fmaf((float)xrf[t][ks][j], (float)x0f[ks][j], p);
        p += __shfl_xor(p, 16, 64);   // sum over quads (dd slices)
        p += __shfl_xor(p, 32, 64);
        float d0 = __builtin_amdgcn_fmed3f(p, -1.0f + EPSF, 1.0f - EPSF);
        float f0 = fused_factor(d0);
#pragma unroll
        for (int r = 0; r < 4; ++r) {
          bf16 cb = (bf16)(wf[t][r] * f0);
          AC[(obase + r) * TS2 + 16 * t + ln15] = cb;  // Ct rows (wave-private)
          sd[r] = fmaf((float)cb, d0, sd[r]);
        }
      }
    } else {
      // ---- GEMM1: dotT[o][i] (B from registers) ----
      f32x4 acc[4] = {f32x4{0,0,0,0}, f32x4{0,0,0,0}, f32x4{0,0,0,0}, f32x4{0,0,0,0}};
#pragma unroll
      for (int ks = 0; ks < 2; ++ks) {
        bf16x8 af = *reinterpret_cast<const bf16x8*>(&acbase[ks * 32 + quad * 8]);
#pragma unroll
        for (int t = 0; t < 4; ++t)
          acc[t] = __builtin_amdgcn_mfma_f32_16x16x32_bf16(af, xrf[t][ks], acc[t], 0, 0, 0);
      }
      // ---- elementwise: c = w * fused_factor(dot); Arow rows become Ct ----
#pragma unroll
      for (int t = 0; t < 4; ++t) {
#pragma unroll
        for (int r = 0; r < 4; ++r) {
          float raw = acc[t][r];
          float dot = __builtin_amdgcn_fmed3f(raw, -1.0f + EPSF, 1.0f - EPSF);
          bf16 cb = (bf16)(wf[t][r] * fused_factor(dot));
          AC[(obase + r) * TS2 + 16 * t + ln15] = cb;  // safe alias (wave-private)
          sd[r] = fmaf((float)cb, dot, sd[r]);
        }
      }
    }
#pragma unroll
    for (int r = 0; r < 4; ++r) sd[r] = dpp_sum16(sd[r]);

    if (it == 0) __syncthreads();  // Xt complete (hidden behind it0 front)

    // ---- GEMM2: G[o][dd] ----
    f32x4 g[4] = {f32x4{0,0,0,0}, f32x4{0,0,0,0}, f32x4{0,0,0,0}, f32x4{0,0,0,0}};
#pragma unroll
    for (int ks = 0; ks < 2; ++ks) {
      bf16x8 af = *reinterpret_cast<const bf16x8*>(&acbase[ks * 32 + quad * 8]);
#pragma unroll
      for (int t = 0; t < 4; ++t) {
        bf16x8 bfr = *reinterpret_cast<const bf16x8*>(
            &Xt[(16 * t + ln15) * TS2 + ks * 32 + quad * 8]);
        g[t] = __builtin_amdgcn_mfma_f32_16x16x32_bf16(af, bfr, g[t], 0, 0, 0);
      }
    }

    // ---- grad = G - sdot*a ; exp map with native trans ops ----
    float gn2[4] = {0.f, 0.f, 0.f, 0.f};
#pragma unroll
    for (int t = 0; t < 4; ++t)
#pragma unroll
      for (int r = 0; r < 4; ++r) {
        float v = g[t][r] - sd[r] * a_reg[t][r];
        g[t][r] = v;
        gn2[r] = fmaf(v, v, gn2[r]);
      }
#pragma unroll
    for (int r = 0; r < 4; ++r) {
      float nrm = __builtin_amdgcn_sqrtf(dpp_sum16(gn2[r]));
      float rev = nrm * 0.15915494309189535f;     // v_sin/v_cos take revolutions
      float sn_ = __builtin_amdgcn_sinf(rev);
      float cn  = __builtin_amdgcn_cosf(rev);
      float sn = (nrm < EPSF) ? 1.0f : sn_ * __builtin_amdgcn_rcpf(nrm);
#pragma unroll
      for (int t = 0; t < 4; ++t)
        a_reg[t][r] = fmaf(cn, a_reg[t][r], sn * g[t][r]);
      if (it < 2) {
        // writeback folded per-r so the LDS drain starts before next GEMM1
#pragma unroll
        for (int t = 0; t < 4; ++t)
          AC[(obase + r) * TS2 + 16 * t + ln15] = (bf16)a_reg[t][r];
      }
    }
  }

  // ---- epilogue: direct stores. For fixed (t,r) each quad-row writes one
  // fully-covered contiguous 64B segment (4 segments/instr) — no LDS, no sync.
  float* outn = out + (size_t)n * 4096;
#pragma unroll
  for (int t = 0; t < 4; ++t)
#pragma unroll
    for (int r = 0; r < 4; ++r)
      outn[(obase + r) * 64 + 16 * t + ln15] = a_reg[t][r];
}

extern "C" void kernel_launch(void* const* d_in, const int* in_sizes, int n_in,
                              void* d_out, int out_size, void* d_ws, size_t ws_size,
                              hipStream_t stream) {
  const float* x = (const float*)d_in[0];    // (B,L,64,64) fp32, unit rows
  const float* wraw = (const float*)d_in[1]; // (64,64) fp32
  float* out = (float*)d_out;                // (B,L,64,64) fp32
  (void)d_ws; (void)ws_size;

  int N = in_sizes[0] / 4096;  // B*L = 1024
  mfd_fc_mfma<<<N, 256, 0, stream>>>(x, wraw, out);
}

// Round 2
// 79.032 us; speedup vs baseline: 1.0474x; 1.0198x over previous
//
#include <hip/hip_runtime.h>

#define EPSF 1e-7f
#define TS2 72   // bf16 row stride: 64 + 8 pad (16B-aligned rows, bank-rotating)

typedef __bf16 bf16;
typedef __attribute__((ext_vector_type(8))) __bf16 bf16x8;
typedef __attribute__((ext_vector_type(4))) __bf16 bf16x4;
typedef __attribute__((ext_vector_type(4))) float f32x4;

// Sum across the 4 quads (lanes ^16, ^32). 2 ops vs dpp_sum16's 8.
__device__ __forceinline__ float quad_sum(float v) {
  v += __shfl_xor(v, 16, 64);
  v += __shfl_xor(v, 32, 64);
  return v;
}

// factor(dot) = acos(dot)/sqrt(1-dot^2) = theta/sin(theta), fused via
// A&S 4.4.45: acos(x)=sqrt(1-x)*P(x) for x>=0. Then
//   dot>=0: P(dot)*rsqrt(1+dot)
//   dot< 0: (pi*rsqrt(1-|dot|) - P(|dot|)) * rsqrt(1+|dot|)
// 2 v_rsq + ~7 VALU.
__device__ __forceinline__ float fused_factor(float dot) {
  float ax = fabsf(dot);
  float q2 = __builtin_amdgcn_rsqf(1.0f + ax);
  float r2 = __builtin_amdgcn_rsqf(1.0f - ax);   // dot clamped -> 1-ax >= EPSF
  float pa = fmaf(fmaf(fmaf(-0.0187292994f, ax, 0.0742610070f), ax,
                       -0.2121144013f), ax, 1.5707288f);
  float sel = (dot < 0.0f) ? fmaf(3.14159265358979f, r2, -pa) : pa;
  return sel * q2;
}

// One block = one sample n; 4 waves; wave wv owns o-channels [16wv,16wv+16).
// BOTH GEMMs use swapped operand roles (A/B frag layouts are identical on
// gfx950, so this is just argument order; LDS addresses unchanged):
//   GEMM1: dot[i][o] = mfma(A=X(xrf regs), B=a-rows(AC))   -> lane owns o=olane
//   GEMM2: G^T[dd][o]= mfma(A=Xt-rows,     B=c-rows(AC))   -> lane owns o=olane
// With o fixed per lane (olane=16wv+ln15), every per-o reduction (softmax
// sum, sd, ||grad||^2) is a lane-local 16-sum + 2 shfl_xor, and the exp-map
// transcendental set runs ONCE per lane (was 4x + 4 dpp trees).
// it0 rank-1 path: d0[i]=<x0,xi> at ln15-i layout, redistributed to the
// (16t+4quad+r)-i layout via 32 ds_bpermute, once.
// Barrier schedule: [stage Xrow] sync [hoists + Xt build + it0 front]
// sync-once [GEMM2 it0; iters 1,2 barrier-free] [4x float4 direct stores].
__global__ __launch_bounds__(256, 4) void mfd_fc_mfma(
    const float* __restrict__ x, const float* __restrict__ wraw,
    float* __restrict__ out) {
  __shared__ __align__(16) char smem[3 * 64 * TS2 * sizeof(bf16)];  // 27648 B
  bf16* Xrow = (bf16*)smem;            // [i][dd]
  bf16* Xt   = Xrow + 64 * TS2;        // [dd][i]
  bf16* AC   = Xt + 64 * TS2;          // [o][dd] as a-rows / [o][i] as c-rows

  const int n = blockIdx.x;
  const int tid = threadIdx.x;
  const int wv = tid >> 6;
  const int lane = tid & 63;
  const int ln15 = lane & 15;
  const int quad = lane >> 4;
  const int q4 = 4 * quad;
  const int olane = 16 * wv + ln15;    // this lane's output channel
  const float* xn = x + (size_t)n * 4096;

  // ---- stage X -> Xrow (bf16), coalesced float4 loads ----
#pragma unroll
  for (int t = 0; t < 4; ++t) {
    int idx = tid + t * 256;  // float4 index
    int i = idx >> 4;
    int c4 = (idx & 15) << 2;
    float4 v = reinterpret_cast<const float4*>(xn)[idx];
    bf16x4 b;
    b[0] = (bf16)v.x; b[1] = (bf16)v.y; b[2] = (bf16)v.z; b[3] = (bf16)v.w;
    *reinterpret_cast<bf16x4*>(&Xrow[i * TS2 + c4]) = b;
  }

  // ---- softmax of wraw column o=olane, transposed layout:
  // wf2[t][r] = w[i=16t+q4+r][olane], normalized over i (lane sum + quads)
  float wf2[4][4];
  {
    float cs = 0.f;
#pragma unroll
    for (int t = 0; t < 4; ++t)
#pragma unroll
      for (int r = 0; r < 4; ++r) {
        float e = __expf(wraw[(16 * t + q4 + r) * 64 + olane]);
        wf2[t][r] = e;
        cs += e;
      }
    float inv = __builtin_amdgcn_rcpf(quad_sum(cs));
#pragma unroll
    for (int t = 0; t < 4; ++t)
#pragma unroll
      for (int r = 0; r < 4; ++r) wf2[t][r] *= inv;
  }

  // ---- a := x0, transposed layout: a_reg[t][r] = x0[dd=16t+q4+r] ----
  float a_reg[4][4];
#pragma unroll
  for (int t = 0; t < 4; ++t) {
    float4 v = *reinterpret_cast<const float4*>(&xn[16 * t + q4]);
    a_reg[t][0] = v.x; a_reg[t][1] = v.y; a_reg[t][2] = v.z; a_reg[t][3] = v.w;
  }

  __syncthreads();  // Xrow complete

  // ---- hoist GEMM1 A-fragments (X rows, loop-invariant): 8 x bf16x8 ----
  bf16x8 xrf[4][2];
#pragma unroll
  for (int t = 0; t < 4; ++t)
#pragma unroll
    for (int ks = 0; ks < 2; ++ks)
      xrf[t][ks] = *reinterpret_cast<const bf16x8*>(
          &Xrow[(16 * t + ln15) * TS2 + ks * 32 + quad * 8]);

  // ---- x0 fragment (row 0; per-quad broadcast read) for the it0 rank-1 dot
  bf16x8 x0f[2];
#pragma unroll
  for (int ks = 0; ks < 2; ++ks)
    x0f[ks] = *reinterpret_cast<const bf16x8*>(&Xrow[ks * 32 + quad * 8]);

  // ---- build Xt from Xrow (u16 column reads = pair-broadcast) ----
  {
    int dd = tid & 63, ih = tid >> 6;  // i-range [16*ih, 16*ih+16)
    bf16 tmp[16];
#pragma unroll
    for (int j = 0; j < 16; ++j) tmp[j] = Xrow[(16 * ih + j) * TS2 + dd];
    *reinterpret_cast<bf16x8*>(&Xt[dd * TS2 + 16 * ih]) =
        *reinterpret_cast<bf16x8*>(&tmp[0]);
    *reinterpret_cast<bf16x8*>(&Xt[dd * TS2 + 16 * ih + 8]) =
        *reinterpret_cast<bf16x8*>(&tmp[8]);
  }
  // NOTE: no barrier yet — it0 front only touches Xrow-derived regs + AC.

  bf16* acrow = &AC[olane * TS2];   // lane's private o-row (a-row / c-row)

  for (int it = 0; it < 3; ++it) {
    float sdv = 0.f;
    if (it == 0) {
      // ---- rank-1 it0: d0[i] = <x0, x_i>, independent of o ----
      float d0[4], f0[4];
#pragma unroll
      for (int t = 0; t < 4; ++t) {
        float p = 0.f;
#pragma unroll
        for (int ks = 0; ks < 2; ++ks)
#pragma unroll
          for (int j = 0; j < 8; ++j)
            p = fmaf((float)xrf[t][ks][j], (float)x0f[ks][j], p);
        p = quad_sum(p);   // full dd sum; uniform across quads
        d0[t] = __builtin_amdgcn_fmed3f(p, -1.0f + EPSF, 1.0f - EPSF);
        f0[t] = fused_factor(d0[t]);
      }
      // redistribute i=16t+ln15 -> i=16t+q4+r (same-row bpermute; values
      // are quad-uniform so the own-quad source row is valid)
      const int srcb = (lane & 48) + q4;
#pragma unroll
      for (int t = 0; t < 4; ++t)
#pragma unroll
        for (int r = 0; r < 4; ++r) {
          float d0n = __shfl(d0[t], srcb + r, 64);
          float f0n = __shfl(f0[t], srcb + r, 64);
          bf16 cb = (bf16)(wf2[t][r] * f0n);
          acrow[16 * t + q4 + r] = cb;          // c-row [olane][i]
          sdv = fmaf((float)cb, d0n, sdv);
        }
    } else {
      // ---- GEMM1 (swapped): dot[i][o]; A=xrf regs, B=a-row from AC ----
      f32x4 acc[4] = {f32x4{0,0,0,0}, f32x4{0,0,0,0}, f32x4{0,0,0,0}, f32x4{0,0,0,0}};
#pragma unroll
      for (int ks = 0; ks < 2; ++ks) {
        bf16x8 bfA = *reinterpret_cast<const bf16x8*>(&acrow[ks * 32 + quad * 8]);
#pragma unroll
        for (int t = 0; t < 4; ++t)
          acc[t] = __builtin_amdgcn_mfma_f32_16x16x32_bf16(xrf[t][ks], bfA, acc[t], 0, 0, 0);
      }
      // ---- elementwise: c = w * factor(dot); lane covers i=16t+q4+r, o=olane
#pragma unroll
      for (int t = 0; t < 4; ++t) {
#pragma unroll
        for (int r = 0; r < 4; ++r) {
          float raw = acc[t][r];
          float dot = __builtin_amdgcn_fmed3f(raw, -1.0f + EPSF, 1.0f - EPSF);
          bf16 cb = (bf16)(wf2[t][r] * fused_factor(dot));
          acrow[16 * t + q4 + r] = cb;          // c-row overwrites a-row (in-order)
          sdv = fmaf((float)cb, dot, sdv);
        }
      }
    }
    sdv = quad_sum(sdv);   // sd[olane] = sum_i c*dot

    if (it == 0) __syncthreads();  // Xt complete (hidden behind it0 front)

    // ---- GEMM2 (swapped): G^T[dd][o]; A=Xt rows, B=c-row from AC ----
    f32x4 g[4] = {f32x4{0,0,0,0}, f32x4{0,0,0,0}, f32x4{0,0,0,0}, f32x4{0,0,0,0}};
#pragma unroll
    for (int ks = 0; ks < 2; ++ks) {
      bf16x8 cf = *reinterpret_cast<const bf16x8*>(&acrow[ks * 32 + quad * 8]);
#pragma unroll
      for (int t = 0; t < 4; ++t) {
        bf16x8 xtf = *reinterpret_cast<const bf16x8*>(
            &Xt[(16 * t + ln15) * TS2 + ks * 32 + quad * 8]);
        g[t] = __builtin_amdgcn_mfma_f32_16x16x32_bf16(xtf, cf, g[t], 0, 0, 0);
      }
    }

    // ---- grad = G - sd*a ; exp map — ONE transcendental set per lane ----
    float gn2 = 0.f;
#pragma unroll
    for (int t = 0; t < 4; ++t)
#pragma unroll
      for (int r = 0; r < 4; ++r) {
        float v = g[t][r] - sdv * a_reg[t][r];
        g[t][r] = v;
        gn2 = fmaf(v, v, gn2);
      }
    gn2 = quad_sum(gn2);
    float nrm = __builtin_amdgcn_sqrtf(gn2);
    float rev = nrm * 0.15915494309189535f;     // v_sin/v_cos take revolutions
    float sn_ = __builtin_amdgcn_sinf(rev);
    float cn  = __builtin_amdgcn_cosf(rev);
    float sn = (nrm < EPSF) ? 1.0f : sn_ * __builtin_amdgcn_rcpf(nrm);
#pragma unroll
    for (int t = 0; t < 4; ++t)
#pragma unroll
      for (int r = 0; r < 4; ++r)
        a_reg[t][r] = fmaf(cn, a_reg[t][r], sn * g[t][r]);
    if (it < 2) {
      // a-row writeback [olane][dd] for next GEMM1's B-frag
#pragma unroll
      for (int t = 0; t < 4; ++t)
#pragma unroll
        for (int r = 0; r < 4; ++r)
          acrow[16 * t + q4 + r] = (bf16)a_reg[t][r];
    }
  }

  // ---- epilogue: 4 float4 direct stores; each quad-row covers a
  // contiguous 64B segment of its o-row. No LDS, no sync.
  float* outn = out + (size_t)n * 4096;
#pragma unroll
  for (int t = 0; t < 4; ++t) {
    float4 v4;
    v4.x = a_reg[t][0]; v4.y = a_reg[t][1];
    v4.z = a_reg[t][2]; v4.w = a_reg[t][3];
    *reinterpret_cast<float4*>(&outn[olane * 64 + 16 * t + q4]) = v4;
  }
}

extern "C" void kernel_launch(void* const* d_in, const int* in_sizes, int n_in,
                              void* d_out, int out_size, void* d_ws, size_t ws_size,
                              hipStream_t stream) {
  const float* x = (const float*)d_in[0];    // (B,L,64,64) fp32, unit rows
  const float* wraw = (const float*)d_in[1]; // (64,64) fp32
  float* out = (float*)d_out;                // (B,L,64,64) fp32
  (void)d_ws; (void)ws_size;

  int N = in_sizes[0] / 4096;  // B*L = 1024
  mfd_fc_mfma<<<N, 256, 0, stream>>>(x, wraw, out);
}

// Round 3
// 78.911 us; speedup vs baseline: 1.0490x; 1.0015x over previous
//
#include <hip/hip_runtime.h>

#define EPSF 1e-7f
#define TS2 72   // bf16 row stride: 64 + 8 pad (16B-aligned rows, bank-rotating)

typedef __bf16 bf16;
typedef __attribute__((ext_vector_type(8))) __bf16 bf16x8;
typedef __attribute__((ext_vector_type(4))) __bf16 bf16x4;
typedef __attribute__((ext_vector_type(4))) float f32x4;

// Sum across the 4 quads (lanes ^16, ^32). 2 ops vs dpp_sum16's 8.
__device__ __forceinline__ float quad_sum(float v) {
  v += __shfl_xor(v, 16, 64);
  v += __shfl_xor(v, 32, 64);
  return v;
}

// factor(dot) = acos(dot)/sqrt(1-dot^2) = theta/sin(theta), fused via
// A&S 4.4.45: acos(x)=sqrt(1-x)*P(x) for x>=0. Then
//   dot>=0: P(dot)*rsqrt(1+dot)
//   dot< 0: (pi*rsqrt(1-|dot|) - P(|dot|)) * rsqrt(1+|dot|)
// 2 v_rsq + ~7 VALU.
__device__ __forceinline__ float fused_factor(float dot) {
  float ax = fabsf(dot);
  float q2 = __builtin_amdgcn_rsqf(1.0f + ax);
  float r2 = __builtin_amdgcn_rsqf(1.0f - ax);   // dot clamped -> 1-ax >= EPSF
  float pa = fmaf(fmaf(fmaf(-0.0187292994f, ax, 0.0742610070f), ax,
                       -0.2121144013f), ax, 1.5707288f);
  float sel = (dot < 0.0f) ? fmaf(3.14159265358979f, r2, -pa) : pa;
  return sel * q2;
}

// One block = one sample n; 4 waves; wave wv owns o-channels [16wv,16wv+16).
// BOTH GEMMs use swapped operand roles (A/B frag layouts are identical on
// gfx950, so this is just argument order; LDS addresses unchanged):
//   GEMM1: dot[i][o] = mfma(A=X(xrf regs), B=a-rows(AC))   -> lane owns o=olane
//   GEMM2: G^T[dd][o]= mfma(A=Xt-rows,     B=c-rows(AC))   -> lane owns o=olane
// With o fixed per lane (olane=16wv+ln15), every per-o reduction (softmax
// sum, sd, ||grad||^2) is a lane-local 16-sum + 2 shfl_xor, and the exp-map
// transcendental set runs ONCE per lane.
// This revision: all AC row writes (c-row, a-row, it0 c-row) packed as
// bf16x4 -> ds_write_b64 (4 instead of 16 scalar u16 writes per site; the
// 4 scalar cvts fuse to 2 v_cvt_pk_bf16_f32, bit-identical RNE) — shortens
// the lgkm drain the dependent GEMM B-frag reads sit behind.
// Barrier schedule: [stage Xrow] sync [hoists + Xt build + it0 front]
// sync-once [GEMM2 it0; iters 1,2 barrier-free] [4x float4 direct stores].
__global__ __launch_bounds__(256, 4) void mfd_fc_mfma(
    const float* __restrict__ x, const float* __restrict__ wraw,
    float* __restrict__ out) {
  __shared__ __align__(16) char smem[3 * 64 * TS2 * sizeof(bf16)];  // 27648 B
  bf16* Xrow = (bf16*)smem;            // [i][dd]
  bf16* Xt   = Xrow + 64 * TS2;        // [dd][i]
  bf16* AC   = Xt + 64 * TS2;          // [o][dd] as a-rows / [o][i] as c-rows

  const int n = blockIdx.x;
  const int tid = threadIdx.x;
  const int wv = tid >> 6;
  const int lane = tid & 63;
  const int ln15 = lane & 15;
  const int quad = lane >> 4;
  const int q4 = 4 * quad;
  const int olane = 16 * wv + ln15;    // this lane's output channel
  const float* xn = x + (size_t)n * 4096;

  // ---- stage X -> Xrow (bf16), coalesced float4 loads ----
#pragma unroll
  for (int t = 0; t < 4; ++t) {
    int idx = tid + t * 256;  // float4 index
    int i = idx >> 4;
    int c4 = (idx & 15) << 2;
    float4 v = reinterpret_cast<const float4*>(xn)[idx];
    bf16x4 b;
    b[0] = (bf16)v.x; b[1] = (bf16)v.y; b[2] = (bf16)v.z; b[3] = (bf16)v.w;
    *reinterpret_cast<bf16x4*>(&Xrow[i * TS2 + c4]) = b;
  }

  // ---- softmax of wraw column o=olane, transposed layout:
  // wf2[t][r] = w[i=16t+q4+r][olane], normalized over i (lane sum + quads)
  float wf2[4][4];
  {
    float cs = 0.f;
#pragma unroll
    for (int t = 0; t < 4; ++t)
#pragma unroll
      for (int r = 0; r < 4; ++r) {
        float e = __expf(wraw[(16 * t + q4 + r) * 64 + olane]);
        wf2[t][r] = e;
        cs += e;
      }
    float inv = __builtin_amdgcn_rcpf(quad_sum(cs));
#pragma unroll
    for (int t = 0; t < 4; ++t)
#pragma unroll
      for (int r = 0; r < 4; ++r) wf2[t][r] *= inv;
  }

  // ---- a := x0, transposed layout: a_reg[t][r] = x0[dd=16t+q4+r] ----
  float a_reg[4][4];
#pragma unroll
  for (int t = 0; t < 4; ++t) {
    float4 v = *reinterpret_cast<const float4*>(&xn[16 * t + q4]);
    a_reg[t][0] = v.x; a_reg[t][1] = v.y; a_reg[t][2] = v.z; a_reg[t][3] = v.w;
  }

  __syncthreads();  // Xrow complete

  // ---- hoist GEMM1 A-fragments (X rows, loop-invariant): 8 x bf16x8 ----
  bf16x8 xrf[4][2];
#pragma unroll
  for (int t = 0; t < 4; ++t)
#pragma unroll
    for (int ks = 0; ks < 2; ++ks)
      xrf[t][ks] = *reinterpret_cast<const bf16x8*>(
          &Xrow[(16 * t + ln15) * TS2 + ks * 32 + quad * 8]);

  // ---- x0 fragment (row 0; per-quad broadcast read) for the it0 rank-1 dot
  bf16x8 x0f[2];
#pragma unroll
  for (int ks = 0; ks < 2; ++ks)
    x0f[ks] = *reinterpret_cast<const bf16x8*>(&Xrow[ks * 32 + quad * 8]);

  // ---- build Xt from Xrow (u16 column reads = pair-broadcast) ----
  {
    int dd = tid & 63, ih = tid >> 6;  // i-range [16*ih, 16*ih+16)
    bf16 tmp[16];
#pragma unroll
    for (int j = 0; j < 16; ++j) tmp[j] = Xrow[(16 * ih + j) * TS2 + dd];
    *reinterpret_cast<bf16x8*>(&Xt[dd * TS2 + 16 * ih]) =
        *reinterpret_cast<bf16x8*>(&tmp[0]);
    *reinterpret_cast<bf16x8*>(&Xt[dd * TS2 + 16 * ih + 8]) =
        *reinterpret_cast<bf16x8*>(&tmp[8]);
  }
  // NOTE: no barrier yet — it0 front only touches Xrow-derived regs + AC.

  bf16* acrow = &AC[olane * TS2];   // lane's private o-row (a-row / c-row)

  for (int it = 0; it < 3; ++it) {
    float sdv = 0.f;
    if (it == 0) {
      // ---- rank-1 it0: d0[i] = <x0, x_i>, independent of o ----
      float d0[4], f0[4];
#pragma unroll
      for (int t = 0; t < 4; ++t) {
        float p = 0.f;
#pragma unroll
        for (int ks = 0; ks < 2; ++ks)
#pragma unroll
          for (int j = 0; j < 8; ++j)
            p = fmaf((float)xrf[t][ks][j], (float)x0f[ks][j], p);
        p = quad_sum(p);   // full dd sum; uniform across quads
        d0[t] = __builtin_amdgcn_fmed3f(p, -1.0f + EPSF, 1.0f - EPSF);
        f0[t] = fused_factor(d0[t]);
      }
      // redistribute i=16t+ln15 -> i=16t+q4+r (same-quad bpermute; values
      // are quad-uniform so the own-quad source row is valid); pack c-row
      const int srcb = (lane & 48) + q4;
#pragma unroll
      for (int t = 0; t < 4; ++t) {
        bf16x4 cpk;
#pragma unroll
        for (int r = 0; r < 4; ++r) {
          float d0n = __shfl(d0[t], srcb + r, 64);
          float f0n = __shfl(f0[t], srcb + r, 64);
          bf16 cb = (bf16)(wf2[t][r] * f0n);
          cpk[r] = cb;
          sdv = fmaf((float)cb, d0n, sdv);
        }
        *reinterpret_cast<bf16x4*>(&acrow[16 * t + q4]) = cpk;  // c-row b64
      }
    } else {
      // ---- GEMM1 (swapped): dot[i][o]; A=xrf regs, B=a-row from AC ----
      f32x4 acc[4] = {f32x4{0,0,0,0}, f32x4{0,0,0,0}, f32x4{0,0,0,0}, f32x4{0,0,0,0}};
#pragma unroll
      for (int ks = 0; ks < 2; ++ks) {
        bf16x8 bfA = *reinterpret_cast<const bf16x8*>(&acrow[ks * 32 + quad * 8]);
#pragma unroll
        for (int t = 0; t < 4; ++t)
          acc[t] = __builtin_amdgcn_mfma_f32_16x16x32_bf16(xrf[t][ks], bfA, acc[t], 0, 0, 0);
      }
      // ---- elementwise: c = w * factor(dot); lane covers i=16t+q4+r, o=olane
#pragma unroll
      for (int t = 0; t < 4; ++t) {
        bf16x4 cpk;
#pragma unroll
        for (int r = 0; r < 4; ++r) {
          float raw = acc[t][r];
          float dot = __builtin_amdgcn_fmed3f(raw, -1.0f + EPSF, 1.0f - EPSF);
          bf16 cb = (bf16)(wf2[t][r] * fused_factor(dot));
          cpk[r] = cb;
          sdv = fmaf((float)cb, dot, sdv);
        }
        *reinterpret_cast<bf16x4*>(&acrow[16 * t + q4]) = cpk;  // c-row b64
      }
    }
    sdv = quad_sum(sdv);   // sd[olane] = sum_i c*dot

    if (it == 0) __syncthreads();  // Xt complete (hidden behind it0 front)

    // ---- GEMM2 (swapped): G^T[dd][o]; A=Xt rows, B=c-row from AC ----
    f32x4 g[4] = {f32x4{0,0,0,0}, f32x4{0,0,0,0}, f32x4{0,0,0,0}, f32x4{0,0,0,0}};
#pragma unroll
    for (int ks = 0; ks < 2; ++ks) {
      bf16x8 cf = *reinterpret_cast<const bf16x8*>(&acrow[ks * 32 + quad * 8]);
#pragma unroll
      for (int t = 0; t < 4; ++t) {
        bf16x8 xtf = *reinterpret_cast<const bf16x8*>(
            &Xt[(16 * t + ln15) * TS2 + ks * 32 + quad * 8]);
        g[t] = __builtin_amdgcn_mfma_f32_16x16x32_bf16(xtf, cf, g[t], 0, 0, 0);
      }
    }

    // ---- grad = G - sd*a ; exp map — ONE transcendental set per lane ----
    float gn2 = 0.f;
#pragma unroll
    for (int t = 0; t < 4; ++t)
#pragma unroll
      for (int r = 0; r < 4; ++r) {
        float v = g[t][r] - sdv * a_reg[t][r];
        g[t][r] = v;
        gn2 = fmaf(v, v, gn2);
      }
    gn2 = quad_sum(gn2);
    float nrm = __builtin_amdgcn_sqrtf(gn2);
    float rev = nrm * 0.15915494309189535f;     // v_sin/v_cos take revolutions
    float sn_ = __builtin_amdgcn_sinf(rev);
    float cn  = __builtin_amdgcn_cosf(rev);
    float sn = (nrm < EPSF) ? 1.0f : sn_ * __builtin_amdgcn_rcpf(nrm);
#pragma unroll
    for (int t = 0; t < 4; ++t)
#pragma unroll
      for (int r = 0; r < 4; ++r)
        a_reg[t][r] = fmaf(cn, a_reg[t][r], sn * g[t][r]);
    if (it < 2) {
      // a-row writeback [olane][dd] for next GEMM1's B-frag, packed b64
#pragma unroll
      for (int t = 0; t < 4; ++t) {
        bf16x4 apk;
#pragma unroll
        for (int r = 0; r < 4; ++r) apk[r] = (bf16)a_reg[t][r];
        *reinterpret_cast<bf16x4*>(&acrow[16 * t + q4]) = apk;
      }
    }
  }

  // ---- epilogue: 4 float4 direct stores; each quad-row covers a
  // contiguous 64B segment of its o-row. No LDS, no sync.
  float* outn = out + (size_t)n * 4096;
#pragma unroll
  for (int t = 0; t < 4; ++t) {
    float4 v4;
    v4.x = a_reg[t][0]; v4.y = a_reg[t][1];
    v4.z = a_reg[t][2]; v4.w = a_reg[t][3];
    *reinterpret_cast<float4*>(&outn[olane * 64 + 16 * t + q4]) = v4;
  }
}

extern "C" void kernel_launch(void* const* d_in, const int* in_sizes, int n_in,
                              void* d_out, int out_size, void* d_ws, size_t ws_size,
                              hipStream_t stream) {
  const float* x = (const float*)d_in[0];    // (B,L,64,64) fp32, unit rows
  const float* wraw = (const float*)d_in[1]; // (64,64) fp32
  float* out = (float*)d_out;                // (B,L,64,64) fp32
  (void)d_ws; (void)ws_size;

  int N = in_sizes[0] / 4096;  // B*L = 1024
  mfd_fc_mfma<<<N, 256, 0, stream>>>(x, wraw, out);
}

// Round 4
// 78.383 us; speedup vs baseline: 1.0561x; 1.0067x over previous
//
#include <hip/hip_runtime.h>

#define EPSF 1e-7f
#define TS2 72   // bf16 row stride: 64 + 8 pad (16B-aligned rows, bank-rotating)

typedef __bf16 bf16;
typedef __attribute__((ext_vector_type(8))) __bf16 bf16x8;
typedef __attribute__((ext_vector_type(4))) __bf16 bf16x4;
typedef __attribute__((ext_vector_type(4))) float f32x4;
typedef __attribute__((ext_vector_type(2))) float f32x2;

// Sum across the 4 quads (lanes ^16, ^32). 2 ops.
__device__ __forceinline__ float quad_sum(float v) {
  v += __shfl_xor(v, 16, 64);
  v += __shfl_xor(v, 32, 64);
  return v;
}

// factor(dot) = acos(dot)/sqrt(1-dot^2) = theta/sin(theta), fused via
// A&S 4.4.45: acos(x)=sqrt(1-x)*P(x) for x>=0. Then
//   dot>=0: P(dot)*rsqrt(1+dot)
//   dot< 0: (pi*rsqrt(1-|dot|) - P(|dot|)) * rsqrt(1+|dot|)
// 2 v_rsq + ~7 VALU.
__device__ __forceinline__ float fused_factor(float dot) {
  float ax = fabsf(dot);
  float q2 = __builtin_amdgcn_rsqf(1.0f + ax);
  float r2 = __builtin_amdgcn_rsqf(1.0f - ax);   // dot clamped -> 1-ax >= EPSF
  float pa = fmaf(fmaf(fmaf(-0.0187292994f, ax, 0.0742610070f), ax,
                       -0.2121144013f), ax, 1.5707288f);
  float sel = (dot < 0.0f) ? fmaf(3.14159265358979f, r2, -pa) : pa;
  return sel * q2;
}

// One block = one sample n; 4 waves; wave wv owns o-channels [16wv,16wv+16).
// BOTH GEMMs use swapped operand roles (A/B frag layouts are identical on
// gfx950):
//   GEMM1: dot[i][o] = mfma(A=X(xrf regs), B=a-row)  -> lane owns o=olane
//   GEMM2: G^T[dd][o]= mfma(A=Xt-rows,     B=c-row)  -> lane owns o=olane
// it0 is UNIFIED into the loop: a0 == x0, and x0f (registers) already has
// the exact B-frag layout, so GEMM1-it0 = mfma(xrf, x0f) with no LDS read
// and no AC dependency — d0 lands directly at acc[t][r] (i=16t+q4+r).
// This removes the former rank-1 VALU dot + 32-bpermute redistribution.
// grad/gn2/a-update blocks run on f32x2 (static-indexed) -> v_pk_fma_f32.
// Barrier schedule: [stage Xrow] sync [hoists + Xt build + it0 front]
// sync-once [GEMM2 it0; iters 1,2 barrier-free] [4x float4 direct stores].
__global__ __launch_bounds__(256, 4) void mfd_fc_mfma(
    const float* __restrict__ x, const float* __restrict__ wraw,
    float* __restrict__ out) {
  __shared__ __align__(16) char smem[3 * 64 * TS2 * sizeof(bf16)];  // 27648 B
  bf16* Xrow = (bf16*)smem;            // [i][dd]
  bf16* Xt   = Xrow + 64 * TS2;        // [dd][i]
  bf16* AC   = Xt + 64 * TS2;          // [o][dd] as a-rows / [o][i] as c-rows

  const int n = blockIdx.x;
  const int tid = threadIdx.x;
  const int wv = tid >> 6;
  const int lane = tid & 63;
  const int ln15 = lane & 15;
  const int quad = lane >> 4;
  const int q4 = 4 * quad;
  const int olane = 16 * wv + ln15;    // this lane's output channel
  const float* xn = x + (size_t)n * 4096;

  // ---- stage X -> Xrow (bf16), coalesced float4 loads ----
#pragma unroll
  for (int t = 0; t < 4; ++t) {
    int idx = tid + t * 256;  // float4 index
    int i = idx >> 4;
    int c4 = (idx & 15) << 2;
    float4 v = reinterpret_cast<const float4*>(xn)[idx];
    bf16x4 b;
    b[0] = (bf16)v.x; b[1] = (bf16)v.y; b[2] = (bf16)v.z; b[3] = (bf16)v.w;
    *reinterpret_cast<bf16x4*>(&Xrow[i * TS2 + c4]) = b;
  }

  // ---- softmax of wraw column o=olane, transposed layout:
  // wf2[t][r] = w[i=16t+q4+r][olane], normalized over i (lane sum + quads)
  float wf2[4][4];
  {
    float cs = 0.f;
#pragma unroll
    for (int t = 0; t < 4; ++t)
#pragma unroll
      for (int r = 0; r < 4; ++r) {
        float e = __expf(wraw[(16 * t + q4 + r) * 64 + olane]);
        wf2[t][r] = e;
        cs += e;
      }
    float inv = __builtin_amdgcn_rcpf(quad_sum(cs));
#pragma unroll
    for (int t = 0; t < 4; ++t)
#pragma unroll
      for (int r = 0; r < 4; ++r) wf2[t][r] *= inv;
  }

  // ---- a := x0, transposed layout: a_reg[t][r] = x0[dd=16t+q4+r] ----
  float a_reg[4][4];
#pragma unroll
  for (int t = 0; t < 4; ++t) {
    float4 v = *reinterpret_cast<const float4*>(&xn[16 * t + q4]);
    a_reg[t][0] = v.x; a_reg[t][1] = v.y; a_reg[t][2] = v.z; a_reg[t][3] = v.w;
  }

  __syncthreads();  // Xrow complete

  // ---- hoist GEMM1 A-fragments (X rows, loop-invariant): 8 x bf16x8 ----
  bf16x8 xrf[4][2];
#pragma unroll
  for (int t = 0; t < 4; ++t)
#pragma unroll
    for (int ks = 0; ks < 2; ++ks)
      xrf[t][ks] = *reinterpret_cast<const bf16x8*>(
          &Xrow[(16 * t + ln15) * TS2 + ks * 32 + quad * 8]);

  // ---- x0 B-fragment (row 0; chunk depends only on ks,quad — exactly the
  // B-frag layout) for the unified it0 GEMM1
  bf16x8 x0f[2];
#pragma unroll
  for (int ks = 0; ks < 2; ++ks)
    x0f[ks] = *reinterpret_cast<const bf16x8*>(&Xrow[ks * 32 + quad * 8]);

  // ---- build Xt from Xrow (u16 column reads = pair-broadcast) ----
  {
    int dd = tid & 63, ih = tid >> 6;  // i-range [16*ih, 16*ih+16)
    bf16 tmp[16];
#pragma unroll
    for (int j = 0; j < 16; ++j) tmp[j] = Xrow[(16 * ih + j) * TS2 + dd];
    *reinterpret_cast<bf16x8*>(&Xt[dd * TS2 + 16 * ih]) =
        *reinterpret_cast<bf16x8*>(&tmp[0]);
    *reinterpret_cast<bf16x8*>(&Xt[dd * TS2 + 16 * ih + 8]) =
        *reinterpret_cast<bf16x8*>(&tmp[8]);
  }
  // NOTE: no barrier yet — it0 front (MFMA on registers) doesn't touch Xt.

  bf16* acrow = &AC[olane * TS2];   // lane's private o-row (a-row / c-row)
  f32x2* a2 = reinterpret_cast<f32x2*>(&a_reg[0][0]);  // static-indexed only

#pragma unroll
  for (int it = 0; it < 3; ++it) {
    // ---- GEMM1 (swapped): dot[i][o]; A=xrf regs, B = x0f (it0) / a-row ----
    f32x4 acc[4] = {f32x4{0,0,0,0}, f32x4{0,0,0,0}, f32x4{0,0,0,0}, f32x4{0,0,0,0}};
#pragma unroll
    for (int ks = 0; ks < 2; ++ks) {
      bf16x8 bfA = (it == 0)
          ? x0f[ks]
          : *reinterpret_cast<const bf16x8*>(&acrow[ks * 32 + quad * 8]);
#pragma unroll
      for (int t = 0; t < 4; ++t)
        acc[t] = __builtin_amdgcn_mfma_f32_16x16x32_bf16(xrf[t][ks], bfA, acc[t], 0, 0, 0);
    }

    // ---- elementwise: c = w * factor(dot); lane covers i=16t+q4+r, o=olane
    float sdv = 0.f;
#pragma unroll
    for (int t = 0; t < 4; ++t) {
      bf16x4 cpk;
#pragma unroll
      for (int r = 0; r < 4; ++r) {
        float raw = acc[t][r];
        float dot = __builtin_amdgcn_fmed3f(raw, -1.0f + EPSF, 1.0f - EPSF);
        bf16 cb = (bf16)(wf2[t][r] * fused_factor(dot));
        cpk[r] = cb;
        sdv = fmaf((float)cb, dot, sdv);
      }
      *reinterpret_cast<bf16x4*>(&acrow[16 * t + q4]) = cpk;  // c-row b64
    }
    sdv = quad_sum(sdv);   // sd[olane] = sum_i c*dot

    if (it == 0) __syncthreads();  // Xt complete (hidden behind it0 front)

    // ---- GEMM2 (swapped): G^T[dd][o]; A=Xt rows, B=c-row from AC ----
    f32x4 g[4] = {f32x4{0,0,0,0}, f32x4{0,0,0,0}, f32x4{0,0,0,0}, f32x4{0,0,0,0}};
#pragma unroll
    for (int ks = 0; ks < 2; ++ks) {
      bf16x8 cf = *reinterpret_cast<const bf16x8*>(&acrow[ks * 32 + quad * 8]);
#pragma unroll
      for (int t = 0; t < 4; ++t) {
        bf16x8 xtf = *reinterpret_cast<const bf16x8*>(
            &Xt[(16 * t + ln15) * TS2 + ks * 32 + quad * 8]);
        g[t] = __builtin_amdgcn_mfma_f32_16x16x32_bf16(xtf, cf, g[t], 0, 0, 0);
      }
    }

    // ---- grad = G - sd*a ; exp map — packed f32 pairs (v_pk_fma_f32) ----
    f32x2* g2 = reinterpret_cast<f32x2*>(&g[0]);   // static-indexed only
    f32x2 sdv2 = {sdv, sdv};
    f32x2 gn2v = {0.f, 0.f};
#pragma unroll
    for (int u = 0; u < 8; ++u) {
      f32x2 v = g2[u] - sdv2 * a2[u];
      g2[u] = v;
      gn2v = v * v + gn2v;
    }
    float gn2 = quad_sum(gn2v.x + gn2v.y);
    float nrm = __builtin_amdgcn_sqrtf(gn2);
    float rev = nrm * 0.15915494309189535f;     // v_sin/v_cos take revolutions
    float sn_ = __builtin_amdgcn_sinf(rev);
    float cn  = __builtin_amdgcn_cosf(rev);
    float sn = (nrm < EPSF) ? 1.0f : sn_ * __builtin_amdgcn_rcpf(nrm);
    f32x2 cn2 = {cn, cn}, sn2 = {sn, sn};
#pragma unroll
    for (int u = 0; u < 8; ++u)
      a2[u] = cn2 * a2[u] + sn2 * g2[u];
    if (it < 2) {
      // a-row writeback [olane][dd] for next GEMM1's B-frag, packed b64
#pragma unroll
      for (int t = 0; t < 4; ++t) {
        bf16x4 apk;
#pragma unroll
        for (int r = 0; r < 4; ++r) apk[r] = (bf16)a_reg[t][r];
        *reinterpret_cast<bf16x4*>(&acrow[16 * t + q4]) = apk;
      }
    }
  }

  // ---- epilogue: 4 float4 direct stores; each quad-row covers a
  // contiguous 64B segment of its o-row. No LDS, no sync.
  float* outn = out + (size_t)n * 4096;
#pragma unroll
  for (int t = 0; t < 4; ++t) {
    float4 v4;
    v4.x = a_reg[t][0]; v4.y = a_reg[t][1];
    v4.z = a_reg[t][2]; v4.w = a_reg[t][3];
    *reinterpret_cast<float4*>(&outn[olane * 64 + 16 * t + q4]) = v4;
  }
}

extern "C" void kernel_launch(void* const* d_in, const int* in_sizes, int n_in,
                              void* d_out, int out_size, void* d_ws, size_t ws_size,
                              hipStream_t stream) {
  const float* x = (const float*)d_in[0];    // (B,L,64,64) fp32, unit rows
  const float* wraw = (const float*)d_in[1]; // (64,64) fp32
  float* out = (float*)d_out;                // (B,L,64,64) fp32
  (void)d_ws; (void)ws_size;

  int N = in_sizes[0] / 4096;  // B*L = 1024
  mfd_fc_mfma<<<N, 256, 0, stream>>>(x, wraw, out);
}

// Round 6
// 78.144 us; speedup vs baseline: 1.0593x; 1.0031x over previous
//
#include <hip/hip_runtime.h>

#define EPSF 1e-7f
#define TS2 72   // bf16 row stride: 64 + 8 pad (16B-aligned rows, bank-rotating)

typedef __bf16 bf16;
typedef __attribute__((ext_vector_type(8))) __bf16 bf16x8;
typedef __attribute__((ext_vector_type(4))) __bf16 bf16x4;
typedef __attribute__((ext_vector_type(4))) float f32x4;
typedef __attribute__((ext_vector_type(2))) float f32x2;

// Sum across the 4 quads (lanes ^16, ^32). 2 ops.
__device__ __forceinline__ float quad_sum(float v) {
  v += __shfl_xor(v, 16, 64);
  v += __shfl_xor(v, 32, 64);
  return v;
}

// One block = one sample n; 4 waves; wave wv owns o-channels [16wv,16wv+16).
// BOTH GEMMs use swapped operand roles (A/B frag layouts are identical on
// gfx950):
//   GEMM1: dot[i][o] = mfma(A=X(xrf regs), B=a-row)  -> lane owns o=olane
//   GEMM2: G^T[dd][o]= mfma(A=Xt-rows,     B=c-row)  -> lane owns o=olane
// it0 UNIFIED: a0 == x0 and x0f (regs) already has the B-frag layout, so
// GEMM1-it0 = mfma(xrf, x0f) with no LDS read.
// This revision: the elementwise factor pipeline
//   factor(dot) = acos(dot)/sqrt(1-dot^2)   (A&S 4.4.45 fused form:
//   dot>=0: P(ax)*rsq(1+ax); dot<0: (pi*rsq(1-ax)-P(ax))*rsq(1+ax))
// runs PAIRWISE on f32x2 (v_pk_add/mul/fma_f32; |x| via pk_max with neg),
// as do the softmax accumulate/normalize and the sdv accumulation.
// rsq/fmed3/cmp/cndmask/cvt stay scalar. Same rounding points as scalar.
// Barrier schedule: [stage Xrow] sync [hoists + Xt build + it0 front]
// sync-once [GEMM2 it0; iters 1,2 barrier-free] [4x float4 direct stores].
__global__ __launch_bounds__(256, 4) void mfd_fc_mfma(
    const float* __restrict__ x, const float* __restrict__ wraw,
    float* __restrict__ out) {
  __shared__ __align__(16) char smem[3 * 64 * TS2 * sizeof(bf16)];  // 27648 B
  bf16* Xrow = (bf16*)smem;            // [i][dd]
  bf16* Xt   = Xrow + 64 * TS2;        // [dd][i]
  bf16* AC   = Xt + 64 * TS2;          // [o][dd] as a-rows / [o][i] as c-rows

  const int n = blockIdx.x;
  const int tid = threadIdx.x;
  const int wv = tid >> 6;
  const int lane = tid & 63;
  const int ln15 = lane & 15;
  const int quad = lane >> 4;
  const int q4 = 4 * quad;
  const int olane = 16 * wv + ln15;    // this lane's output channel
  const float* xn = x + (size_t)n * 4096;

  const f32x2 ONE2 = {1.0f, 1.0f};
  const f32x2 PC3 = {-0.0187292994f, -0.0187292994f};
  const f32x2 PC2 = {0.0742610070f, 0.0742610070f};
  const f32x2 PC1 = {-0.2121144013f, -0.2121144013f};
  const f32x2 PC0 = {1.5707288f, 1.5707288f};
  const f32x2 PI2 = {3.14159265358979f, 3.14159265358979f};

  // ---- stage X -> Xrow (bf16), coalesced float4 loads ----
#pragma unroll
  for (int t = 0; t < 4; ++t) {
    int idx = tid + t * 256;  // float4 index
    int i = idx >> 4;
    int c4 = (idx & 15) << 2;
    float4 v = reinterpret_cast<const float4*>(xn)[idx];
    bf16x4 b;
    b[0] = (bf16)v.x; b[1] = (bf16)v.y; b[2] = (bf16)v.z; b[3] = (bf16)v.w;
    *reinterpret_cast<bf16x4*>(&Xrow[i * TS2 + c4]) = b;
  }

  // ---- softmax of wraw column o=olane, transposed layout, packed pairs:
  // wfp[t][h] = {w[16t+q4+2h][olane], w[16t+q4+2h+1][olane]} normalized
  f32x2 wfp[4][2];
  {
    f32x2 cs2 = {0.f, 0.f};
#pragma unroll
    for (int t = 0; t < 4; ++t)
#pragma unroll
      for (int h = 0; h < 2; ++h) {
        f32x2 e;
        e.x = __expf(wraw[(16 * t + q4 + 2 * h) * 64 + olane]);
        e.y = __expf(wraw[(16 * t + q4 + 2 * h + 1) * 64 + olane]);
        wfp[t][h] = e;
        cs2 = cs2 + e;                  // pk_add
      }
    float inv = __builtin_amdgcn_rcpf(quad_sum(cs2.x + cs2.y));
    f32x2 inv2 = {inv, inv};
#pragma unroll
    for (int t = 0; t < 4; ++t)
#pragma unroll
      for (int h = 0; h < 2; ++h) wfp[t][h] = wfp[t][h] * inv2;  // pk_mul
  }

  // ---- a := x0, transposed layout: a_reg[t][r] = x0[dd=16t+q4+r] ----
  float a_reg[4][4];
#pragma unroll
  for (int t = 0; t < 4; ++t) {
    float4 v = *reinterpret_cast<const float4*>(&xn[16 * t + q4]);
    a_reg[t][0] = v.x; a_reg[t][1] = v.y; a_reg[t][2] = v.z; a_reg[t][3] = v.w;
  }

  __syncthreads();  // Xrow complete

  // ---- hoist GEMM1 A-fragments (X rows, loop-invariant): 8 x bf16x8 ----
  bf16x8 xrf[4][2];
#pragma unroll
  for (int t = 0; t < 4; ++t)
#pragma unroll
    for (int ks = 0; ks < 2; ++ks)
      xrf[t][ks] = *reinterpret_cast<const bf16x8*>(
          &Xrow[(16 * t + ln15) * TS2 + ks * 32 + quad * 8]);

  // ---- x0 B-fragment (row 0; chunk depends only on ks,quad — exactly the
  // B-frag layout) for the unified it0 GEMM1
  bf16x8 x0f[2];
#pragma unroll
  for (int ks = 0; ks < 2; ++ks)
    x0f[ks] = *reinterpret_cast<const bf16x8*>(&Xrow[ks * 32 + quad * 8]);

  // ---- build Xt from Xrow (u16 column reads = pair-broadcast) ----
  {
    int dd = tid & 63, ih = tid >> 6;  // i-range [16*ih, 16*ih+16)
    bf16 tmp[16];
#pragma unroll
    for (int j = 0; j < 16; ++j) tmp[j] = Xrow[(16 * ih + j) * TS2 + dd];
    *reinterpret_cast<bf16x8*>(&Xt[dd * TS2 + 16 * ih]) =
        *reinterpret_cast<bf16x8*>(&tmp[0]);
    *reinterpret_cast<bf16x8*>(&Xt[dd * TS2 + 16 * ih + 8]) =
        *reinterpret_cast<bf16x8*>(&tmp[8]);
  }
  // NOTE: no barrier yet — it0 front (MFMA on registers) doesn't touch Xt.

  bf16* acrow = &AC[olane * TS2];   // lane's private o-row (a-row / c-row)
  f32x2* a2 = reinterpret_cast<f32x2*>(&a_reg[0][0]);  // static-indexed only

#pragma unroll
  for (int it = 0; it < 3; ++it) {
    // ---- GEMM1 (swapped): dot[i][o]; A=xrf regs, B = x0f (it0) / a-row ----
    f32x4 acc[4] = {f32x4{0,0,0,0}, f32x4{0,0,0,0}, f32x4{0,0,0,0}, f32x4{0,0,0,0}};
#pragma unroll
    for (int ks = 0; ks < 2; ++ks) {
      bf16x8 bfA = (it == 0)
          ? x0f[ks]
          : *reinterpret_cast<const bf16x8*>(&acrow[ks * 32 + quad * 8]);
#pragma unroll
      for (int t = 0; t < 4; ++t)
        acc[t] = __builtin_amdgcn_mfma_f32_16x16x32_bf16(xrf[t][ks], bfA, acc[t], 0, 0, 0);
    }

    // ---- elementwise: c = w * factor(dot), packed pairs over r ----
    float sdv;
    {
      f32x2 sdp = {0.f, 0.f};
#pragma unroll
      for (int t = 0; t < 4; ++t) {
        bf16x4 cpk;
#pragma unroll
        for (int h = 0; h < 2; ++h) {
          f32x2 d2;
          d2.x = __builtin_amdgcn_fmed3f(acc[t][2 * h],     -1.0f + EPSF, 1.0f - EPSF);
          d2.y = __builtin_amdgcn_fmed3f(acc[t][2 * h + 1], -1.0f + EPSF, 1.0f - EPSF);
          f32x2 nd = -d2;
          f32x2 ax; ax.x = fmaxf(d2.x, nd.x); ax.y = fmaxf(d2.y, nd.y);  // pk_max
          f32x2 p1 = ONE2 + ax;                 // pk_add
          f32x2 m1 = ONE2 - ax;                 // pk_add (neg)
          f32x2 q2, r2;
          q2.x = __builtin_amdgcn_rsqf(p1.x); q2.y = __builtin_amdgcn_rsqf(p1.y);
          r2.x = __builtin_amdgcn_rsqf(m1.x); r2.y = __builtin_amdgcn_rsqf(m1.y);
          f32x2 pa = PC3 * ax + PC2;            // 3x pk_fma
          pa = pa * ax + PC1;
          pa = pa * ax + PC0;
          f32x2 nb = PI2 * r2 - pa;             // pk_fma (neg)
          f32x2 sel;
          sel.x = (d2.x < 0.f) ? nb.x : pa.x;
          sel.y = (d2.y < 0.f) ? nb.y : pa.y;
          f32x2 cf = (sel * q2) * wfp[t][h];    // 2x pk_mul
          bf16 c0 = (bf16)cf.x, c1 = (bf16)cf.y;
          cpk[2 * h] = c0; cpk[2 * h + 1] = c1;
          f32x2 cbf; cbf.x = (float)c0; cbf.y = (float)c1;
          sdp = cbf * d2 + sdp;                 // pk_fma
        }
        *reinterpret_cast<bf16x4*>(&acrow[16 * t + q4]) = cpk;  // c-row b64
      }
      sdv = quad_sum(sdp.x + sdp.y);   // sd[olane] = sum_i c*dot
    }

    if (it == 0) __syncthreads();  // Xt complete (hidden behind it0 front)

    // ---- GEMM2 (swapped): G^T[dd][o]; A=Xt rows, B=c-row from AC ----
    f32x4 g[4] = {f32x4{0,0,0,0}, f32x4{0,0,0,0}, f32x4{0,0,0,0}, f32x4{0,0,0,0}};
#pragma unroll
    for (int ks = 0; ks < 2; ++ks) {
      bf16x8 cf = *reinterpret_cast<const bf16x8*>(&acrow[ks * 32 + quad * 8]);
#pragma unroll
      for (int t = 0; t < 4; ++t) {
        bf16x8 xtf = *reinterpret_cast<const bf16x8*>(
            &Xt[(16 * t + ln15) * TS2 + ks * 32 + quad * 8]);
        g[t] = __builtin_amdgcn_mfma_f32_16x16x32_bf16(xtf, cf, g[t], 0, 0, 0);
      }
    }

    // ---- grad = G - sd*a ; exp map — packed f32 pairs (v_pk_fma_f32) ----
    f32x2* g2 = reinterpret_cast<f32x2*>(&g[0]);   // static-indexed only
    f32x2 sdv2 = {sdv, sdv};
    f32x2 gn2v = {0.f, 0.f};
#pragma unroll
    for (int u = 0; u < 8; ++u) {
      f32x2 v = g2[u] - sdv2 * a2[u];
      g2[u] = v;
      gn2v = v * v + gn2v;
    }
    float gn2 = quad_sum(gn2v.x + gn2v.y);
    float nrm = __builtin_amdgcn_sqrtf(gn2);
    float rev = nrm * 0.15915494309189535f;     // v_sin/v_cos take revolutions
    float sn_ = __builtin_amdgcn_sinf(rev);
    float cn  = __builtin_amdgcn_cosf(rev);
    float sn = (nrm < EPSF) ? 1.0f : sn_ * __builtin_amdgcn_rcpf(nrm);
    f32x2 cn2 = {cn, cn}, sn2 = {sn, sn};
#pragma unroll
    for (int u = 0; u < 8; ++u)
      a2[u] = cn2 * a2[u] + sn2 * g2[u];
    if (it < 2) {
      // a-row writeback [olane][dd] for next GEMM1's B-frag, packed b64
#pragma unroll
      for (int t = 0; t < 4; ++t) {
        bf16x4 apk;
#pragma unroll
        for (int r = 0; r < 4; ++r) apk[r] = (bf16)a_reg[t][r];
        *reinterpret_cast<bf16x4*>(&acrow[16 * t + q4]) = apk;
      }
    }
  }

  // ---- epilogue: 4 float4 direct stores; each quad-row covers a
  // contiguous 64B segment of its o-row. No LDS, no sync.
  float* outn = out + (size_t)n * 4096;
#pragma unroll
  for (int t = 0; t < 4; ++t) {
    float4 v4;
    v4.x = a_reg[t][0]; v4.y = a_reg[t][1];
    v4.z = a_reg[t][2]; v4.w = a_reg[t][3];
    *reinterpret_cast<float4*>(&outn[olane * 64 + 16 * t + q4]) = v4;
  }
}

extern "C" void kernel_launch(void* const* d_in, const int* in_sizes, int n_in,
                              void* d_out, int out_size, void* d_ws, size_t ws_size,
                              hipStream_t stream) {
  const float* x = (const float*)d_in[0];    // (B,L,64,64) fp32, unit rows
  const float* wraw = (const float*)d_in[1]; // (64,64) fp32
  float* out = (float*)d_out;                // (B,L,64,64) fp32
  (void)d_ws; (void)ws_size;

  int N = in_sizes[0] / 4096;  // B*L = 1024
  mfd_fc_mfma<<<N, 256, 0, stream>>>(x, wraw, out);
}

// Round 7
// 77.701 us; speedup vs baseline: 1.0653x; 1.0057x over previous
//
#include <hip/hip_runtime.h>

#define EPSF 1e-7f
#define TS2 72   // bf16 row stride: 64 + 8 pad (144 B = 16B-aligned rows)

typedef __bf16 bf16;
typedef __attribute__((ext_vector_type(8))) __bf16 bf16x8;
typedef __attribute__((ext_vector_type(4))) __bf16 bf16x4;
typedef __attribute__((ext_vector_type(4))) float f32x4;
typedef __attribute__((ext_vector_type(2))) float f32x2;

// Sum across the 4 quads (lanes ^16, ^32). 2 ops.
__device__ __forceinline__ float quad_sum(float v) {
  v += __shfl_xor(v, 16, 64);
  v += __shfl_xor(v, 32, 64);
  return v;
}

// One block = one sample n; 4 waves; wave wv owns o-channels [16wv,16wv+16).
// BOTH GEMMs use swapped operand roles (A/B frag layouts are identical on
// gfx950):
//   GEMM1: dot[i][o] = mfma(A=X(xrf regs), B=a-row)  -> lane owns o=olane
//   GEMM2: G^T[dd][o]= mfma(A=Xt-rows,     B=c-row)  -> lane owns o=olane
// it0 UNIFIED: a0 == x0 and x0f (regs) already has the B-frag layout.
// This revision:
//  (1) sd = sum_i c*dot computed as <a,G> AFTER GEMM2 (identity: G=sum c*x
//      => sum c*dot = <a,G>); ||grad||^2 = <G,G> - sd^2 (a unit, guarded
//      with fmax 0); update folded: a' = (cn - sn*sd)*a + sn*G. Removes the
//      in-elementwise sd accumulation (8 pk_fma + 16 cvt + 2 shfl per iter).
//  (2) Xrow/Xt/AC are SEPARATE __shared__ arrays (provably disjoint), so
//      the compiler may schedule Xt/Xrow reads around AC writes freely
//      (single char[] smem forced false-alias ordering).
// Elementwise factor pipeline stays pairwise-packed on f32x2 (v_pk_*).
// Barrier schedule: [stage Xrow] sync [hoists + Xt build + it0 front]
// sync-once [GEMM2 it0; iters 1,2 barrier-free] [4x float4 direct stores].
__global__ __launch_bounds__(256, 4) void mfd_fc_mfma(
    const float* __restrict__ x, const float* __restrict__ wraw,
    float* __restrict__ out) {
  __shared__ __align__(16) bf16 Xrow[64 * TS2];  // [i][dd]
  __shared__ __align__(16) bf16 Xt[64 * TS2];    // [dd][i]
  __shared__ __align__(16) bf16 AC[64 * TS2];    // [o][dd] a-rows / [o][i] c-rows

  const int n = blockIdx.x;
  const int tid = threadIdx.x;
  const int wv = tid >> 6;
  const int lane = tid & 63;
  const int ln15 = lane & 15;
  const int quad = lane >> 4;
  const int q4 = 4 * quad;
  const int olane = 16 * wv + ln15;    // this lane's output channel
  const float* xn = x + (size_t)n * 4096;

  const f32x2 ONE2 = {1.0f, 1.0f};
  const f32x2 PC3 = {-0.0187292994f, -0.0187292994f};
  const f32x2 PC2 = {0.0742610070f, 0.0742610070f};
  const f32x2 PC1 = {-0.2121144013f, -0.2121144013f};
  const f32x2 PC0 = {1.5707288f, 1.5707288f};
  const f32x2 PI2 = {3.14159265358979f, 3.14159265358979f};

  // ---- stage X -> Xrow (bf16), coalesced float4 loads ----
#pragma unroll
  for (int t = 0; t < 4; ++t) {
    int idx = tid + t * 256;  // float4 index
    int i = idx >> 4;
    int c4 = (idx & 15) << 2;
    float4 v = reinterpret_cast<const float4*>(xn)[idx];
    bf16x4 b;
    b[0] = (bf16)v.x; b[1] = (bf16)v.y; b[2] = (bf16)v.z; b[3] = (bf16)v.w;
    *reinterpret_cast<bf16x4*>(&Xrow[i * TS2 + c4]) = b;
  }

  // ---- softmax of wraw column o=olane, transposed layout, packed pairs:
  // wfp[t][h] = {w[16t+q4+2h][olane], w[16t+q4+2h+1][olane]} normalized
  f32x2 wfp[4][2];
  {
    f32x2 cs2 = {0.f, 0.f};
#pragma unroll
    for (int t = 0; t < 4; ++t)
#pragma unroll
      for (int h = 0; h < 2; ++h) {
        f32x2 e;
        e.x = __expf(wraw[(16 * t + q4 + 2 * h) * 64 + olane]);
        e.y = __expf(wraw[(16 * t + q4 + 2 * h + 1) * 64 + olane]);
        wfp[t][h] = e;
        cs2 = cs2 + e;                  // pk_add
      }
    float inv = __builtin_amdgcn_rcpf(quad_sum(cs2.x + cs2.y));
    f32x2 inv2 = {inv, inv};
#pragma unroll
    for (int t = 0; t < 4; ++t)
#pragma unroll
      for (int h = 0; h < 2; ++h) wfp[t][h] = wfp[t][h] * inv2;  // pk_mul
  }

  // ---- a := x0, transposed layout: a_reg[t][r] = x0[dd=16t+q4+r] ----
  float a_reg[4][4];
#pragma unroll
  for (int t = 0; t < 4; ++t) {
    float4 v = *reinterpret_cast<const float4*>(&xn[16 * t + q4]);
    a_reg[t][0] = v.x; a_reg[t][1] = v.y; a_reg[t][2] = v.z; a_reg[t][3] = v.w;
  }

  __syncthreads();  // Xrow complete

  // ---- hoist GEMM1 A-fragments (X rows, loop-invariant): 8 x bf16x8 ----
  bf16x8 xrf[4][2];
#pragma unroll
  for (int t = 0; t < 4; ++t)
#pragma unroll
    for (int ks = 0; ks < 2; ++ks)
      xrf[t][ks] = *reinterpret_cast<const bf16x8*>(
          &Xrow[(16 * t + ln15) * TS2 + ks * 32 + quad * 8]);

  // ---- x0 B-fragment (row 0; chunk depends only on ks,quad — exactly the
  // B-frag layout) for the unified it0 GEMM1
  bf16x8 x0f[2];
#pragma unroll
  for (int ks = 0; ks < 2; ++ks)
    x0f[ks] = *reinterpret_cast<const bf16x8*>(&Xrow[ks * 32 + quad * 8]);

  // ---- build Xt from Xrow (u16 column reads = pair-broadcast) ----
  {
    int dd = tid & 63, ih = tid >> 6;  // i-range [16*ih, 16*ih+16)
    bf16 tmp[16];
#pragma unroll
    for (int j = 0; j < 16; ++j) tmp[j] = Xrow[(16 * ih + j) * TS2 + dd];
    *reinterpret_cast<bf16x8*>(&Xt[dd * TS2 + 16 * ih]) =
        *reinterpret_cast<bf16x8*>(&tmp[0]);
    *reinterpret_cast<bf16x8*>(&Xt[dd * TS2 + 16 * ih + 8]) =
        *reinterpret_cast<bf16x8*>(&tmp[8]);
  }
  // NOTE: no barrier yet — it0 front (MFMA on registers) doesn't touch Xt.

  bf16* acrow = &AC[olane * TS2];   // lane's private o-row (a-row / c-row)
  f32x2* a2 = reinterpret_cast<f32x2*>(&a_reg[0][0]);  // static-indexed only

#pragma unroll
  for (int it = 0; it < 3; ++it) {
    // ---- GEMM1 (swapped): dot[i][o]; A=xrf regs, B = x0f (it0) / a-row ----
    f32x4 acc[4] = {f32x4{0,0,0,0}, f32x4{0,0,0,0}, f32x4{0,0,0,0}, f32x4{0,0,0,0}};
#pragma unroll
    for (int ks = 0; ks < 2; ++ks) {
      bf16x8 bfA = (it == 0)
          ? x0f[ks]
          : *reinterpret_cast<const bf16x8*>(&acrow[ks * 32 + quad * 8]);
#pragma unroll
      for (int t = 0; t < 4; ++t)
        acc[t] = __builtin_amdgcn_mfma_f32_16x16x32_bf16(xrf[t][ks], bfA, acc[t], 0, 0, 0);
    }

    // ---- elementwise: c = w * factor(dot), packed pairs (no sd here) ----
#pragma unroll
    for (int t = 0; t < 4; ++t) {
      bf16x4 cpk;
#pragma unroll
      for (int h = 0; h < 2; ++h) {
        f32x2 d2;
        d2.x = __builtin_amdgcn_fmed3f(acc[t][2 * h],     -1.0f + EPSF, 1.0f - EPSF);
        d2.y = __builtin_amdgcn_fmed3f(acc[t][2 * h + 1], -1.0f + EPSF, 1.0f - EPSF);
        f32x2 nd = -d2;
        f32x2 ax; ax.x = fmaxf(d2.x, nd.x); ax.y = fmaxf(d2.y, nd.y);  // pk_max
        f32x2 p1 = ONE2 + ax;                 // pk_add
        f32x2 m1 = ONE2 - ax;                 // pk_add (neg)
        f32x2 q2, r2;
        q2.x = __builtin_amdgcn_rsqf(p1.x); q2.y = __builtin_amdgcn_rsqf(p1.y);
        r2.x = __builtin_amdgcn_rsqf(m1.x); r2.y = __builtin_amdgcn_rsqf(m1.y);
        f32x2 pa = PC3 * ax + PC2;            // 3x pk_fma
        pa = pa * ax + PC1;
        pa = pa * ax + PC0;
        f32x2 nb = PI2 * r2 - pa;             // pk_fma (neg)
        f32x2 sel;
        sel.x = (d2.x < 0.f) ? nb.x : pa.x;
        sel.y = (d2.y < 0.f) ? nb.y : pa.y;
        f32x2 cf = (sel * q2) * wfp[t][h];    // 2x pk_mul
        cpk[2 * h]     = (bf16)cf.x;
        cpk[2 * h + 1] = (bf16)cf.y;
      }
      *reinterpret_cast<bf16x4*>(&acrow[16 * t + q4]) = cpk;  // c-row b64
    }

    if (it == 0) __syncthreads();  // Xt complete (hidden behind it0 front)

    // ---- GEMM2 (swapped): G^T[dd][o]; A=Xt rows, B=c-row from AC ----
    f32x4 g[4] = {f32x4{0,0,0,0}, f32x4{0,0,0,0}, f32x4{0,0,0,0}, f32x4{0,0,0,0}};
#pragma unroll
    for (int ks = 0; ks < 2; ++ks) {
      bf16x8 cf = *reinterpret_cast<const bf16x8*>(&acrow[ks * 32 + quad * 8]);
#pragma unroll
      for (int t = 0; t < 4; ++t) {
        bf16x8 xtf = *reinterpret_cast<const bf16x8*>(
            &Xt[(16 * t + ln15) * TS2 + ks * 32 + quad * 8]);
        g[t] = __builtin_amdgcn_mfma_f32_16x16x32_bf16(xtf, cf, g[t], 0, 0, 0);
      }
    }

    // ---- sd = <a,G>, gg = <G,G>  (a is unit: ||G - sd*a||^2 = gg - sd^2)
    f32x2* g2 = reinterpret_cast<f32x2*>(&g[0]);   // static-indexed only
    f32x2 sdp = {0.f, 0.f}, ggp = {0.f, 0.f};
#pragma unroll
    for (int u = 0; u < 8; ++u) {
      sdp = a2[u] * g2[u] + sdp;    // pk_fma
      ggp = g2[u] * g2[u] + ggp;    // pk_fma
    }
    float sdv = quad_sum(sdp.x + sdp.y);
    float gg  = quad_sum(ggp.x + ggp.y);
    float gn2 = fmaxf(gg - sdv * sdv, 0.f);     // guard rounding-negative
    float nrm = __builtin_amdgcn_sqrtf(gn2);
    float rev = nrm * 0.15915494309189535f;     // v_sin/v_cos take revolutions
    float sn_ = __builtin_amdgcn_sinf(rev);
    float cn  = __builtin_amdgcn_cosf(rev);
    float sn = (nrm < EPSF) ? 1.0f : sn_ * __builtin_amdgcn_rcpf(nrm);
    // a' = cn*a + sn*(G - sd*a) = (cn - sn*sd)*a + sn*G
    float coefA = cn - sn * sdv;
    f32x2 cA2 = {coefA, coefA}, sn2 = {sn, sn};
#pragma unroll
    for (int u = 0; u < 8; ++u)
      a2[u] = cA2 * a2[u] + sn2 * g2[u];
    if (it < 2) {
      // a-row writeback [olane][dd] for next GEMM1's B-frag, packed b64
#pragma unroll
      for (int t = 0; t < 4; ++t) {
        bf16x4 apk;
#pragma unroll
        for (int r = 0; r < 4; ++r) apk[r] = (bf16)a_reg[t][r];
        *reinterpret_cast<bf16x4*>(&acrow[16 * t + q4]) = apk;
      }
    }
  }

  // ---- epilogue: 4 float4 direct stores; each quad-row covers a
  // contiguous 64B segment of its o-row. No LDS, no sync.
  float* outn = out + (size_t)n * 4096;
#pragma unroll
  for (int t = 0; t < 4; ++t) {
    float4 v4;
    v4.x = a_reg[t][0]; v4.y = a_reg[t][1];
    v4.z = a_reg[t][2]; v4.w = a_reg[t][3];
    *reinterpret_cast<float4*>(&outn[olane * 64 + 16 * t + q4]) = v4;
  }
}

extern "C" void kernel_launch(void* const* d_in, const int* in_sizes, int n_in,
                              void* d_out, int out_size, void* d_ws, size_t ws_size,
                              hipStream_t stream) {
  const float* x = (const float*)d_in[0];    // (B,L,64,64) fp32, unit rows
  const float* wraw = (const float*)d_in[1]; // (64,64) fp32
  float* out = (float*)d_out;                // (B,L,64,64) fp32
  (void)d_ws; (void)ws_size;

  int N = in_sizes[0] / 4096;  // B*L = 1024
  mfd_fc_mfma<<<N, 256, 0, stream>>>(x, wraw, out);
}